// Round 5
// baseline (85.742 us; speedup 1.0000x reference)
//
#include <hip/hip_runtime.h>
#include <math.h>

#define BB 8
#define HH 256
#define WW 256
#define T  2     // rows per fused block (must divide 64)
#define NW 4     // 256 rows / 64 bits
#define PAD 40   // envelope window padding; R>PAD handled by exact fallback
#define LDSW (WW + 2 * PAD)

typedef unsigned long long u64;

// ---------------------------------------------------------------------------
// K0: per-column class presence bitmasks + zero the output accumulator.
// masks[((b*4 + k)*NW + w)*WW + x] bit ly  <=>  tgt[b][w*64+ly][x] == k
// ---------------------------------------------------------------------------
__global__ __launch_bounds__(256) void build_masks(const int* __restrict__ tgt,
                                                   u64* __restrict__ masks,
                                                   float* __restrict__ out) {
  const int x = threadIdx.x;
  const int b = blockIdx.x;
  const int w = blockIdx.y;
  if (b == 0 && w == 0 && x == 0) out[0] = 0.0f;  // ordered before fused's atomics
  u64 m0 = 0, m1 = 0, m2 = 0, m3 = 0, bit = 1ull;
  const int* p = tgt + ((size_t)b * HH + w * 64) * WW + x;
  for (int ly = 0; ly < 64; ++ly, bit += bit) {
    int e = p[ly * WW];                 // coalesced across x, L2-resident
    m0 |= (e == 0) ? bit : 0ull;
    m1 |= (e == 1) ? bit : 0ull;
    m2 |= (e == 2) ? bit : 0ull;
    m3 |= (e == 3) ? bit : 0ull;
  }
  const size_t base = (size_t)b * 4 * NW * WW + (size_t)w * WW + x;
  masks[base + 0 * NW * WW] = m0;
  masks[base + 1 * NW * WW] = m1;
  masks[base + 2 * NW * WW] = m2;
  masks[base + 3 * NW * WW] = m3;
}

// ---------------------------------------------------------------------------
// K1 fused: bitmask column-EDT -> u16-packed padded LDS -> exact +/- paired
// envelope (per-wave radius, d^2 computed on the fly) -> softmax epilogue ->
// block reduce -> one atomicAdd.
// Exactness notes: 1-D distances <= 768 fit u16; min(da,db)^2 == min(da^2,db^2)
// for nonnegatives; all candidates are integers < 2^24, exact in fp32.
// Pad value 1023: 1023^2 = 1046529 > 768^2 = 589824 >= kk=0 seed, never wins.
// ---------------------------------------------------------------------------
__global__ __launch_bounds__(256, 4) void fused(const u64* __restrict__ masks,
                                                const int* __restrict__ tgt,
                                                const float* __restrict__ preds,
                                                float* __restrict__ out) {
  __shared__ ushort4 g16[T][LDSW];  // packed 1-D column distances, 4 classes
  __shared__ float fred[4];
  const int x  = threadIdx.x;
  const int b  = blockIdx.x;
  const int y0 = blockIdx.y * T;
  const int wy = y0 >> 6;           // T divides 64 -> same word for all tile rows

  // init padding (disjoint from the g16[.][x+PAD] slots written below)
  for (int i = x; i < T * 2 * PAD; i += 256) {
    int j = i / (2 * PAD);
    int q = i - j * (2 * PAD);
    int idx = (q < PAD) ? q : (q + WW);
    g16[j][idx] = make_ushort4(1023, 1023, 1023, 1023);
  }

  // column masks for this x: 4 classes x 4 words
  u64 m[4][NW];
#pragma unroll
  for (int k = 0; k < 4; ++k)
#pragma unroll
    for (int w = 0; w < NW; ++w)
      m[k][w] = masks[(((size_t)b * 4 + k) * NW + w) * WW + x];

  // phase A: exact 1-D distance along the column via nearest-set-bit
  // (identical math to R2/R3, verified absmax 0.0)
  int lmax = 0;
  int dcol[T][4];
#pragma unroll
  for (int j = 0; j < T; ++j) {
    const int y  = y0 + j;
    const int ly = y & 63;
    const int ini = min(513 + y, 768 - y);   // reference INF-scan value
#pragma unroll
    for (int k = 0; k < 4; ++k) {
      int best = ini;
#pragma unroll
      for (int w = 0; w < NW; ++w) {
        u64 bits = m[k][w];
        if (w < wy) {              // wave-uniform branch (wy is scalar)
          int d = y - (w * 64 + 63 - __clzll((long long)bits));
          best = min(best, bits ? d : 1024);
        } else if (w > wy) {
          int d = w * 64 + (__ffsll((long long)bits) - 1) - y;
          best = min(best, bits ? d : 1024);
        } else {
          u64 lo = bits & ((2ull << ly) - 1ull);  // bits 0..ly (ly=63 -> ~0)
          u64 hi = bits >> ly;                    // bit0 == bit ly
          int dl = ly - 63 + __clzll((long long)lo);
          int dh = __ffsll((long long)hi) - 1;
          best = min(best, lo ? dl : 1024);
          best = min(best, hi ? dh : 1024);
        }
      }
      lmax = max(lmax, best);
      dcol[j][k] = best;
    }
    g16[j][x + PAD] = make_ushort4((unsigned short)dcol[j][0],
                                   (unsigned short)dcol[j][1],
                                   (unsigned short)dcol[j][2],
                                   (unsigned short)dcol[j][3]);
  }

  // per-wave radius: for pixel x, candidate |kk| >= dist(x) can't beat the
  // kk=0 seed (kk^2 >= g[x]); dist(x) <= wave-max over own lanes. Exact.
#pragma unroll
  for (int off = 32; off; off >>= 1) lmax = max(lmax, __shfl_xor(lmax, off, 64));
  const int R  = __builtin_amdgcn_readfirstlane(lmax);
  const int Rw = min(R, PAD);
  __syncthreads();

  // seed with own column value (kk = 0); squares are exact ints in fp32
  float d[T][4];
#pragma unroll
  for (int j = 0; j < T; ++j)
#pragma unroll
    for (int k = 0; k < 4; ++k) {
      float f = (float)dcol[j][k];
      d[j][k] = f * f;
    }

  // exact lower envelope, +/- paired, u16 min before squaring
  for (int kk = 1; kk <= Rw; ++kk) {
    float fkk = (float)kk;
    float fk2 = fkk * fkk;
#pragma unroll
    for (int j = 0; j < T; ++j) {
      ushort4 gm = g16[j][x + PAD - kk];
      ushort4 gp = g16[j][x + PAD + kk];
      float f0 = (float)min((unsigned)gm.x, (unsigned)gp.x);
      float f1 = (float)min((unsigned)gm.y, (unsigned)gp.y);
      float f2 = (float)min((unsigned)gm.z, (unsigned)gp.z);
      float f3 = (float)min((unsigned)gm.w, (unsigned)gp.w);
      d[j][0] = fminf(d[j][0], fmaf(f0, f0, fk2));
      d[j][1] = fminf(d[j][1], fmaf(f1, f1, fk2));
      d[j][2] = fminf(d[j][2], fmaf(f2, f2, fk2));
      d[j][3] = fminf(d[j][3], fmaf(f3, f3, fk2));
    }
  }
  if (R > PAD) {                       // exactness fallback; statistically cold
#pragma unroll 1
    for (int kk = PAD + 1; kk <= R; ++kk) {
      int xm = max(x - kk, 0), xp = min(x + kk, WW - 1);
      float dm = (float)(x - xm), dpq = (float)(xp - x);
      float dm2 = dm * dm, dp2 = dpq * dpq;
#pragma unroll
      for (int j = 0; j < T; ++j) {
        ushort4 gm = g16[j][xm + PAD];
        ushort4 gp = g16[j][xp + PAD];
        float a0 = (float)gm.x, b0 = (float)gp.x;
        float a1 = (float)gm.y, b1 = (float)gp.y;
        float a2 = (float)gm.z, b2 = (float)gp.z;
        float a3 = (float)gm.w, b3 = (float)gp.w;
        d[j][0] = fminf(d[j][0], fminf(fmaf(a0, a0, dm2), fmaf(b0, b0, dp2)));
        d[j][1] = fminf(d[j][1], fminf(fmaf(a1, a1, dm2), fmaf(b1, b1, dp2)));
        d[j][2] = fminf(d[j][2], fminf(fmaf(a2, a2, dm2), fmaf(b2, b2, dp2)));
        d[j][3] = fminf(d[j][3], fminf(fmaf(a3, a3, dm2), fmaf(b3, b3, dp2)));
      }
    }
  }

  // epilogue: softmax + boundary map (same math as R3's passing kernel)
  float acc = 0.0f;
#pragma unroll
  for (int j = 0; j < T; ++j) {
    const int y = y0 + j;
    const int t = tgt[((size_t)b * HH + y) * WW + x];
    const float* pb = preds + ((size_t)b * 4 * HH + y) * WW + x;
    float p0 = pb[0 * HH * WW], p1 = pb[1 * HH * WW];
    float p2 = pb[2 * HH * WW], p3 = pb[3 * HH * WW];
    float pm = fmaxf(fmaxf(p0, p1), fmaxf(p2, p3));
    float e0 = expf(p0 - pm), e1 = expf(p1 - pm);
    float e2 = expf(p2 - pm), e3 = expf(p3 - pm);
    float inv = 1.0f / (e0 + e1 + e2 + e3);

    float dn1 = fminf(d[j][0], fminf(d[j][2], d[j][3]));
    float dn2 = fminf(d[j][0], fminf(d[j][1], d[j][3]));
    float dn3 = fminf(d[j][0], fminf(d[j][1], d[j][2]));
    float c1 = (t == 1) ? (1.0f - sqrtf(dn1)) : sqrtf(d[j][1]);
    float c2 = (t == 2) ? (1.0f - sqrtf(dn2)) : sqrtf(d[j][2]);
    float c3 = (t == 3) ? (1.0f - sqrtf(dn3)) : sqrtf(d[j][3]);
    acc += (c1 * e1 + c2 * e2 + c3 * e3) * inv;
  }

  // block reduction -> single atomic
#pragma unroll
  for (int off = 32; off; off >>= 1) acc += __shfl_down(acc, off, 64);
  if ((x & 63) == 0) fred[x >> 6] = acc;
  __syncthreads();
  if (x == 0)
    atomicAdd(out, (fred[0] + fred[1] + fred[2] + fred[3]) *
                       (1.0f / (3.0f * BB * HH * WW)));
}

extern "C" void kernel_launch(void* const* d_in, const int* in_sizes, int n_in,
                              void* d_out, int out_size, void* d_ws, size_t ws_size,
                              hipStream_t stream) {
  const float* preds = (const float*)d_in[0];
  const int*   tgt   = (const int*)d_in[1];
  float* out   = (float*)d_out;
  u64*   masks = (u64*)d_ws;   // 8*4*4*256*8B = 256 KB

  build_masks<<<dim3(BB, NW), 256, 0, stream>>>(tgt, masks, out);
  fused<<<dim3(BB, HH / T), 256, 0, stream>>>(masks, tgt, preds, out);
}